// Round 6
// baseline (138.478 us; speedup 1.0000x reference)
//
#include <hip/hip_runtime.h>

// Problem constants from setup_inputs(): shape (64, 16, 64, 64), fp32, kern=2.
#define N_ 64
#define C_ 16
#define H_ 64
#define W_ 64

// pair_kernel tiling: R5 structure (best measured): 4 i-rows x 8 j-rows per
// tile, D split into 16 chunks of 1024, natural block order.
// tri sets (vaa, vbb): i-tile g needs j-tiles 0..(g>>1) -> 72 tiles/set.
// vab (full): 16 x 8 = 128 tiles. TILES = 72*2 + 128 = 272.
#define TRI_TILES 72
#define TILES 272
#define DCHUNKS 16
#define PAIR_BLOCKS (TILES * DCHUNKS)   // 4352

// NUMERICS: ws stores var' = var * 2ln2. exp(-0.5 d^2/v)/sqrt(v)
//   = exp2(-(d*rsq(v'))^2) * rsq(v') * sqrt(2ln2). 2 transc + ~2.5 pk-VALU/term.
#define TWO_LN2   1.3862943611198906f
#define SQRT_2LN2 1.1774100225154747f

// ws layout (floats): [0..Np) mu_a | [Np..2Np) var'_a | [2Np..3Np) mu_b |
// [3Np..4Np) var'_b | [4Np..4Np+PAIR_BLOCKS) per-block partials.
// Post-mortem ledger:
// R7: atomicAdd tail serialized -> partials + 1-block reduce.
// R8: register prefetch -> VGPR 96, occ 18%, +4%. Register spend loses waves.
// R9: XCD pinning -> +21%. Natural order's locality wins.
// R10: 512-thread blocks -> +23%. Footprint dilution.
// R11: 8x8 tile, traffic cut, VGPR 140 -> SLOWER. Memory system is LATENCY-
//      bound: achieved BW ~ resident waves. Keep VGPR minimal, R5 pattern.
// R12: packed f32 (v_pk_*) + collapsed accs -> pair ~45.6 -> ~37us. WIN.
//      Harness fillBuffer (256MB poison, 43us) now dominates top-5 — fixed.
// R13 (this): LDS double-buffered j-row staging via global_load_lds (16B) +
//      counted vmcnt(2) — pipeline depth at ZERO VGPR cost. Per-wave self-
//      staging (thread t reads floats 4t..4t+3 = wave base + lane*16B), so
//      no __syncthreads in the loop. Failure mode: compiler vmcnt(0) -> flat.

typedef __attribute__((ext_vector_type(2))) float f32x2;

__global__ __launch_bounds__(256) void pool_kernel(
    const float* __restrict__ mu_a, const float* __restrict__ lv_a,
    const float* __restrict__ mu_b, const float* __restrict__ lv_b,
    const int* __restrict__ kern_p, float* __restrict__ ws) {
    const int k = kern_p[0];
    const float LOG2E = 1.44269504088896f;

    if (k == 2) {
        // Fast path: 4 contiguous pooled outputs per thread, all-shift indexing.
        const int Np = (N_ * C_ * H_ * W_) >> 2;  // 1048576
        const int Q  = Np >> 2;                   // 262144 quads per array
        const int total = 4 * Q;
        for (int g = blockIdx.x * blockDim.x + threadIdx.x; g < total;
             g += gridDim.x * blockDim.x) {
            const int a  = g >> 18;               // log2(Q) = 18
            const int r4 = g & (Q - 1);
            const int pw4 = (r4 & 7) << 2;        // Wp=32 -> 8 quads/row
            const int t   = r4 >> 3;
            const int ph  = t & 31;               // Hp=32
            const int nc  = t >> 5;
            const float* src = (a == 0) ? mu_a : (a == 1) ? lv_a : (a == 2) ? mu_b : lv_b;
            const bool is_var = (a & 1);
            const float* p0 = src + nc * (H_ * W_) + (ph * 2) * W_ + pw4 * 2;
            float4 r0a = *(const float4*)(p0);
            float4 r0b = *(const float4*)(p0 + 4);
            float4 r1a = *(const float4*)(p0 + W_);
            float4 r1b = *(const float4*)(p0 + W_ + 4);
            float o0, o1, o2, o3;
            if (is_var) {
#define E_(x) __builtin_amdgcn_exp2f((x) * LOG2E)
                o0 = E_(r0a.x) + E_(r0a.y) + E_(r1a.x) + E_(r1a.y);
                o1 = E_(r0a.z) + E_(r0a.w) + E_(r1a.z) + E_(r1a.w);
                o2 = E_(r0b.x) + E_(r0b.y) + E_(r1b.x) + E_(r1b.y);
                o3 = E_(r0b.z) + E_(r0b.w) + E_(r1b.z) + E_(r1b.w);
#undef E_
                const float s = (1.0f / 16.0f) * TWO_LN2;  // 1/k^4 * 2ln2
                o0 *= s; o1 *= s; o2 *= s; o3 *= s;
            } else {
                o0 = r0a.x + r0a.y + r1a.x + r1a.y;
                o1 = r0a.z + r0a.w + r1a.z + r1a.w;
                o2 = r0b.x + r0b.y + r1b.x + r1b.y;
                o3 = r0b.z + r0b.w + r1b.z + r1b.w;
                const float s = 0.25f;            // 1/k^2
                o0 *= s; o1 *= s; o2 *= s; o3 *= s;
            }
            *(float4*)(ws + (size_t)a * Np + (size_t)r4 * 4) = make_float4(o0, o1, o2, o3);
        }
    } else {
        // Generic fallback (any k dividing 64).
        const int Hp = H_ / k, Wp = W_ / k;
        const int Np = N_ * C_ * Hp * Wp;
        const float inv_k2 = 1.0f / (float)(k * k);
        const float inv_k4 = inv_k2 * inv_k2 * TWO_LN2;   // fold var pre-scale
        const int total = 4 * Np;
        for (int p = blockIdx.x * blockDim.x + threadIdx.x; p < total;
             p += gridDim.x * blockDim.x) {
            const int a  = p / Np;
            const int r  = p - a * Np;
            const int pw = r % Wp;
            const int t1 = r / Wp;
            const int ph = t1 % Hp;
            const int nc = t1 / Hp;
            const float* src = (a == 0) ? mu_a : (a == 1) ? lv_a : (a == 2) ? mu_b : lv_b;
            const bool is_var = (a & 1);
            const int base = nc * (H_ * W_) + (ph * k) * W_ + (pw * k);
            float s = 0.0f;
            for (int dy = 0; dy < k; ++dy) {
                const float* row = src + base + dy * W_;
                for (int dx = 0; dx < k; ++dx) {
                    float x = row[dx];
                    s += is_var ? __builtin_amdgcn_exp2f(x * LOG2E) : x;
                }
            }
            ws[(size_t)a * Np + r] = s * (is_var ? inv_k4 : inv_k2);
        }
    }
}

// Async 16B global->LDS (each lane: 16B from its own gptr; LDS dest =
// wave-uniform lptr + lane*16).
__device__ __forceinline__ void g2lds16(const float* g, float* l) {
    __builtin_amdgcn_global_load_lds(
        (const __attribute__((address_space(1))) void*)g,
        (__attribute__((address_space(3))) void*)l, 16, 0, 0);
}

// Packed 2-term Gaussian chain: v_pk_add / v_pk_mul / v_pk_fma on f32x2,
// scalar rsq/exp2 per component (no packed transcendentals exist).
#define TERM2(ACC, IM, IV, JM, JV)                                     \
    {                                                                  \
        f32x2 v_  = (IV) + (JV);                                       \
        f32x2 rs_; rs_.x = __builtin_amdgcn_rsqf(v_.x);                \
                   rs_.y = __builtin_amdgcn_rsqf(v_.y);                \
        f32x2 d_  = (IM) - (JM);                                       \
        f32x2 t_  = d_ * rs_;                                          \
        f32x2 nt_ = -t_ * t_;                                          \
        f32x2 e_; e_.x = __builtin_amdgcn_exp2f(nt_.x);                \
                  e_.y = __builtin_amdgcn_exp2f(nt_.y);                \
        ACC += e_ * rs_;                                               \
    }

__global__ __launch_bounds__(256) void pair_kernel(float* __restrict__ ws,
                                                   const int* __restrict__ kern_p) {
    const int k = kern_p[0];
    const int D  = C_ * (H_ / k) * (W_ / k);
    const int Np = N_ * D;

    const float* mu_a = ws;
    const float* va   = ws + (size_t)Np;
    const float* mu_b = ws + (size_t)2 * Np;
    const float* vb   = ws + (size_t)3 * Np;
    float* partials   = ws + (size_t)4 * Np;

    // j-row staging: [buf][mu/v][1024 floats] = 16 KB. Each wave w stages and
    // consumes floats [256w, 256w+255] only -> no cross-wave sync needed.
    __shared__ float jbuf[2][2][1024];

    // ---- decode block -> (tile, chunk), R5 natural order ----
    const int c = blockIdx.x & (DCHUNKS - 1);
    const int t = blockIdx.x >> 4;           // DCHUNKS == 16
    int set, it, jt;
    if (t >= 2 * TRI_TILES) {
        set = 2;
        const int tt = t - 2 * TRI_TILES;
        it = tt >> 3;
        jt = tt & 7;
    } else {
        set = (t >= TRI_TILES) ? 1 : 0;
        const int tt = set ? (t - TRI_TILES) : t;
        int g = 0, cum = 0;
        while (cum + (g >> 1) + 1 <= tt) { cum += (g >> 1) + 1; ++g; }
        it = g;
        jt = tt - cum;
    }
    const int i0 = it * 4, j0 = jt * 8;

    const float *mu1, *v1, *mu2, *v2;
    if (set == 0)      { mu1 = mu2 = mu_a; v1 = v2 = va; }
    else if (set == 1) { mu1 = mu2 = mu_b; v1 = v2 = vb; }
    else               { mu1 = mu_a; v1 = va; mu2 = mu_b; v2 = vb; }

    // Uniform-weight tiles: all of set 2 (w=-2) and tri tiles strictly below
    // the diagonal, jt < it>>1 (w=2). Mixed tiles (jt == it>>1): 32 of 272.
    const bool uniform = (set == 2) || (jt < (it >> 1));
    const float wU = (set == 2) ? -2.0f : 2.0f;

    float tot = 0.0f;

    if (D == 16384) {
        const int tid  = (int)threadIdx.x;
        const int wq   = (tid >> 6) << 8;        // wave LDS quarter (floats)
        const int base = (c << 10) + (tid << 2); // per-thread float4 offset
        const float* gjm = mu2 + (size_t)j0 * 16384 + base;  // per-lane src
        const float* gjv = v2  + (size_t)j0 * 16384 + base;

#define STAGE(J8, BUF)                                        \
        { g2lds16(gjm + (size_t)(J8) * 16384, &jbuf[BUF][0][wq]); \
          g2lds16(gjv + (size_t)(J8) * 16384, &jbuf[BUF][1][wq]); }

        // Prologue: issue j0 stage, then i-row register loads.
        STAGE(0, 0)
        f32x2 imlo[4], imhi[4], ivlo[4], ivhi[4];
        #pragma unroll
        for (int ir = 0; ir < 4; ++ir) {
            const float4 m4 = *(const float4*)(mu1 + (size_t)(i0 + ir) * 16384 + base);
            const float4 v4 = *(const float4*)(v1  + (size_t)(i0 + ir) * 16384 + base);
            imlo[ir].x = m4.x; imlo[ir].y = m4.y; imhi[ir].x = m4.z; imhi[ir].y = m4.w;
            ivlo[ir].x = v4.x; ivlo[ir].y = v4.y; ivhi[ir].x = v4.z; ivhi[ir].y = v4.w;
        }

        f32x2 acc2[4];
        #pragma unroll
        for (int ir = 0; ir < 4; ++ir) { acc2[ir].x = 0.0f; acc2[ir].y = 0.0f; }

        #pragma unroll
        for (int j8 = 0; j8 < 8; ++j8) {
            // Issue next stage, then wait so only those 2 remain in flight:
            // buffer j8 (and at j8=0 the i-loads) are then complete.
            if (j8 < 7) {
                STAGE(j8 + 1, (j8 + 1) & 1)
                asm volatile("s_waitcnt vmcnt(2)" ::: "memory");
            } else {
                asm volatile("s_waitcnt vmcnt(0)" ::: "memory");
            }
            __builtin_amdgcn_sched_barrier(0);

            const float4 jm = *(const float4*)&jbuf[j8 & 1][0][tid << 2];
            const float4 jv = *(const float4*)&jbuf[j8 & 1][1][tid << 2];
            f32x2 jmlo, jmhi, jvlo, jvhi;
            jmlo.x = jm.x; jmlo.y = jm.y; jmhi.x = jm.z; jmhi.y = jm.w;
            jvlo.x = jv.x; jvlo.y = jv.y; jvhi.x = jv.z; jvhi.y = jv.w;

            if (uniform) {
                #pragma unroll
                for (int ir = 0; ir < 4; ++ir) {
                    TERM2(acc2[ir], imlo[ir], ivlo[ir], jmlo, jvlo)
                    TERM2(acc2[ir], imhi[ir], ivhi[ir], jmhi, jvhi)
                }
            } else {
                // Mixed tile (tri diagonal band): fold 0/1/2 weight per (ir,j8).
                const int jj = j0 + j8;
                #pragma unroll
                for (int ir = 0; ir < 4; ++ir) {
                    f32x2 a; a.x = 0.0f; a.y = 0.0f;
                    TERM2(a, imlo[ir], ivlo[ir], jmlo, jvlo)
                    TERM2(a, imhi[ir], ivhi[ir], jmhi, jvhi)
                    const int ii = i0 + ir;
                    const float w = (jj > ii) ? 0.0f : (jj == ii) ? 1.0f : 2.0f;
                    tot = fmaf(w, a.x + a.y, tot);
                }
            }
        }
#undef STAGE
        if (uniform) {
            const f32x2 s2 = (acc2[0] + acc2[1]) + (acc2[2] + acc2[3]);
            tot = wU * (s2.x + s2.y);
        }
    } else {
        // Generic fallback: scalar, weight folded per (ir,j8), single scalar
        // accumulator. No LDS staging.
        const int cs = D / DCHUNKS;
        const int lo = c * cs, hi = lo + cs;
        for (int e = lo + (int)threadIdx.x; e < hi; e += 256) {
            #pragma unroll
            for (int j8 = 0; j8 < 8; ++j8) {
                const int jj = j0 + j8;
                const float mj = mu2[(size_t)jj * D + e];
                const float vj = v2 [(size_t)jj * D + e];
                #pragma unroll
                for (int ir = 0; ir < 4; ++ir) {
                    const int ii = i0 + ir;
                    const float w = (set == 2) ? -2.0f
                                  : (jj > ii) ? 0.0f : (jj == ii) ? 1.0f : 2.0f;
                    const float mi = mu1[(size_t)ii * D + e];
                    const float vi = v1 [(size_t)ii * D + e];
                    float v_  = vi + vj;
                    float rs_ = __builtin_amdgcn_rsqf(v_);
                    float d_  = mi - mj;
                    float t_  = d_ * rs_;
                    float e_  = __builtin_amdgcn_exp2f(-(t_ * t_));
                    tot = fmaf(w, e_ * rs_, tot);
                }
            }
        }
    }

    tot *= SQRT_2LN2;   // fold the var'-prescale correction once

    for (int off = 32; off > 0; off >>= 1)
        tot += __shfl_down(tot, off, 64);
    __shared__ float wsum[4];
    const int lane = threadIdx.x & 63;
    const int wid  = threadIdx.x >> 6;
    if (lane == 0) wsum[wid] = tot;
    __syncthreads();
    if (threadIdx.x == 0) {
        partials[blockIdx.x] = wsum[0] + wsum[1] + wsum[2] + wsum[3];
    }
}

// Single block: sum the PAIR_BLOCKS partials into out[0].
__global__ __launch_bounds__(256) void reduce_kernel(const float* __restrict__ ws,
                                                     const int* __restrict__ kern_p,
                                                     float* __restrict__ out) {
    const int k = kern_p[0];
    const int D  = C_ * (H_ / k) * (W_ / k);
    const int Np = N_ * D;
    const float* partials = ws + (size_t)4 * Np;

    float s = 0.0f;
    for (int p = threadIdx.x; p < PAIR_BLOCKS; p += 256) s += partials[p];
    for (int off = 32; off > 0; off >>= 1)
        s += __shfl_down(s, off, 64);
    __shared__ float wsum[4];
    const int lane = threadIdx.x & 63;
    const int wid  = threadIdx.x >> 6;
    if (lane == 0) wsum[wid] = s;
    __syncthreads();
    if (threadIdx.x == 0) out[0] = wsum[0] + wsum[1] + wsum[2] + wsum[3];
}

extern "C" void kernel_launch(void* const* d_in, const int* in_sizes, int n_in,
                              void* d_out, int out_size, void* d_ws, size_t ws_size,
                              hipStream_t stream) {
    const float* mu_a = (const float*)d_in[0];
    const float* lv_a = (const float*)d_in[1];
    const float* mu_b = (const float*)d_in[2];
    const float* lv_b = (const float*)d_in[3];
    const int*   kern = (const int*)d_in[4];
    float* out = (float*)d_out;
    float* ws  = (float*)d_ws;

    pool_kernel<<<4096, 256, 0, stream>>>(mu_a, lv_a, mu_b, lv_b, kern, ws);
    pair_kernel<<<PAIR_BLOCKS, 256, 0, stream>>>(ws, kern);
    reduce_kernel<<<1, 256, 0, stream>>>(ws, kern, out);
}